// Round 4
// baseline (197.340 us; speedup 1.0000x reference)
//
#include <hip/hip_runtime.h>
#include <hip/hip_bf16.h>
#include <stdint.h>

// PatchedVisionExpertMLP — round 20
//   r19: 183.2us, p1 = 81.5us @ MfmaUtil 38% (m97 ceiling). r17/r18 8-phase
//   ports matched learn_hip's FAILURE quadrants (2ph=682TF, broken-8ph=560TF).
//   Root cause found: wave->output mapping must be INTERLEAVED so each phase's
//   all-wave footprint = exactly one staged half-tile. This round: faithful
//   m201 derivation for p1: 256 rows x (128G|128U) cols, wave rows =
//   wr*64+{0..63}u{128..191}, cols = wc*32+{0..31}u{128..159}; phase (qa,qb)
//   touches A-half qa + B-half qb only; stages go per-phase into the OTHER
//   (dead) buffer; vmcnt(4) at phase ends, never 0 until peeled last tile.
//   Interleaving makes gate/up thread-local in the epilogue (no exchange).
//   Scan pads to 256. p2/prep/gather/reduce frozen at r19.

#define TOKENS 4096
#define SEQ    2048
#define DIM    1024
#define FFDIM  4096
#define MAXPAD 4608

typedef __attribute__((ext_vector_type(8))) short bf16x8;
typedef __attribute__((ext_vector_type(4))) float f32x4;

#define GAS __attribute__((address_space(1)))
#define LAS __attribute__((address_space(3)))

__device__ inline unsigned short f2bf(float x) {
    union { float f; unsigned int u; } c; c.f = x;
    unsigned int r = c.u + 0x7FFFu + ((c.u >> 16) & 1u);  // RNE
    return (unsigned short)(r >> 16);
}
__device__ inline float bf2f(unsigned short u) {
    union { unsigned int i; float f; } c; c.i = ((unsigned int)u) << 16;
    return c.f;
}

struct __align__(16) us8 { unsigned short v[8]; };

// ---------- scan: group tokens by expert, pad each segment to 256 ----------
// (256 so gemm_p1's 256-row blocks never straddle the expert boundary;
//  worst case padTot = 4352 <= MAXPAD; bounds stay multiples of 256 so p2's
//  128-row blocks are also expert-uniform.)
__global__ __launch_bounds__(1024) void scan_kernel(const int* __restrict__ tt,
                                                    int* __restrict__ src_of,
                                                    int* __restrict__ counts) {
    __shared__ int wsum[16];
    const int tid  = threadIdx.x;
    const int lane = tid & 63;
    const int wav  = tid >> 6;

    for (int i = tid; i < MAXPAD; i += 1024) src_of[i] = -1;

    const int t0 = tid * 4;
    int v[4], cnt = 0;
#pragma unroll
    for (int j = 0; j < 4; ++j) {
        const int t = t0 + j;
        const int l = t & (SEQ - 1);
        int vis = 0;
        if (l < SEQ - 1) vis = (tt[t] == 1) & (tt[t + 1] == 1);
        v[j] = vis; cnt += vis;
    }

    int s = cnt;
#pragma unroll
    for (int off = 1; off < 64; off <<= 1) {
        const int o = __shfl_up(s, off, 64);
        if (lane >= off) s += o;
    }
    if (lane == 63) wsum[wav] = s;
    __syncthreads();
    if (wav == 0 && lane < 16) {
        int w = wsum[lane];
#pragma unroll
        for (int off = 1; off < 16; off <<= 1) {
            const int o = __shfl_up(w, off, 16);
            if (lane >= off) w += o;
        }
        wsum[lane] = w;
    }
    __syncthreads();

    const int wbase  = wav ? wsum[wav - 1] : 0;
    const int incl   = wbase + s;
    const int excl   = incl - cnt;
    const int totalV = wsum[15];
    const int padNv  = (totalV + 255) & ~255;
    int pv = excl;
    int pl = padNv + (t0 - excl);
#pragma unroll
    for (int j = 0; j < 4; ++j) {
        const int t = t0 + j;
        if (v[j]) src_of[pv++] = t; else src_of[pl++] = t;
    }
    if (tid == 0) {
        const int Nl = TOKENS - totalV;
        counts[0] = padNv;
        counts[1] = padNv + ((Nl + 255) & ~255);
    }
}

__device__ inline void gather_body(const float* __restrict__ hs, const int* __restrict__ src_of,
                                   unsigned short* __restrict__ Xg, int gid) {
    const int row = gid >> 7;
    const int c   = (gid & 127) * 8;
    const int src = src_of[row];
    us8 o;
    if (src >= 0) {
        const float4 a = *reinterpret_cast<const float4*>(hs + (size_t)src * DIM + c);
        const float4 b = *reinterpret_cast<const float4*>(hs + (size_t)src * DIM + c + 4);
        o.v[0] = f2bf(a.x); o.v[1] = f2bf(a.y); o.v[2] = f2bf(a.z); o.v[3] = f2bf(a.w);
        o.v[4] = f2bf(b.x); o.v[5] = f2bf(b.y); o.v[6] = f2bf(b.z); o.v[7] = f2bf(b.w);
    } else {
#pragma unroll
        for (int j = 0; j < 8; ++j) o.v[j] = 0;
    }
    *reinterpret_cast<us8*>(Xg + (size_t)row * DIM + c) = o;
}

__global__ void gather_cast(const float* __restrict__ hs, const int* __restrict__ src_of,
                            unsigned short* __restrict__ Xg) {
    gather_body(hs, src_of, Xg, blockIdx.x * 256 + threadIdx.x);
}

__device__ inline void cast8(const float* __restrict__ in, unsigned short* __restrict__ out, int i) {
    const float4 a = *reinterpret_cast<const float4*>(in + i);
    const float4 b = *reinterpret_cast<const float4*>(in + i + 4);
    us8 o;
    o.v[0] = f2bf(a.x); o.v[1] = f2bf(a.y); o.v[2] = f2bf(a.z); o.v[3] = f2bf(a.w);
    o.v[4] = f2bf(b.x); o.v[5] = f2bf(b.y); o.v[6] = f2bf(b.z); o.v[7] = f2bf(b.w);
    *reinterpret_cast<us8*>(out + i) = o;
}

// ---------- fused prep: y==0 -> gather+cast X; y=1..6 -> cast weight matrix ----------
__global__ void prep_kernel(const float* __restrict__ hs, const int* __restrict__ src_of,
                            unsigned short* __restrict__ Xg,
                            const float* __restrict__ s0, const float* __restrict__ s1,
                            const float* __restrict__ s2, const float* __restrict__ s3,
                            const float* __restrict__ s4, const float* __restrict__ s5,
                            unsigned short* __restrict__ d0, unsigned short* __restrict__ d1,
                            unsigned short* __restrict__ d2, unsigned short* __restrict__ d3,
                            unsigned short* __restrict__ d4, unsigned short* __restrict__ d5) {
    const int m = blockIdx.y;
    if (m == 0) {
        gather_body(hs, src_of, Xg, blockIdx.x * 256 + threadIdx.x);
    } else {
        const int i = (blockIdx.x * 256 + threadIdx.x) * 8;
        if (i >= FFDIM * DIM) return;
        const float* s = (m == 1) ? s0 : (m == 2) ? s1 : (m == 3) ? s2 : (m == 4) ? s3 : (m == 5) ? s4 : s5;
        unsigned short* d = (m == 1) ? d0 : (m == 2) ? d1 : (m == 3) ? d2 : (m == 4) ? d3 : (m == 5) ? d4 : d5;
        cast8(s, d, i);
    }
}

__global__ void cast4_kernel(const float* __restrict__ s0, const float* __restrict__ s1,
                             const float* __restrict__ s2, const float* __restrict__ s3,
                             unsigned short* __restrict__ d0, unsigned short* __restrict__ d1,
                             unsigned short* __restrict__ d2, unsigned short* __restrict__ d3) {
    const int i = (blockIdx.x * 256 + threadIdx.x) * 8;
    const int m = blockIdx.y;
    const float* s = (m == 0) ? s0 : (m == 1) ? s1 : (m == 2) ? s2 : s3;
    unsigned short* d = (m == 0) ? d0 : (m == 1) ? d1 : (m == 2) ? d2 : d3;
    cast8(s, d, i);
}

__global__ void cast2_kernel(const float* __restrict__ s0, const float* __restrict__ s1,
                             unsigned short* __restrict__ d0, unsigned short* __restrict__ d1) {
    const int i = (blockIdx.x * 256 + threadIdx.x) * 8;
    const float* s = blockIdx.y ? s1 : s0;
    unsigned short* d = blockIdx.y ? d1 : d0;
    cast8(s, d, i);
}

// ========== PHASE 1: m201-faithful 4-phase/K-tile, 256 rows x (128G|128U) ==========
// LDS buf rows: a0 = A[0..127], a1 = A[128..255], b0 = G[0..127], b1 = U[0..127].
// Wave (wr in 0..1, wc in 0..3): rows wr*64+{0..63} (qa=0) and +128 (qa=1);
// cols wc*32+{0..31} (qb=0 -> gate) and +128 (qb=1 -> up). Phase (qa,qb)
// footprint over ALL waves = A-half qa + B-half qb exactly.
// Per K-tile t: ph1 (0,0) stage a0(t+1) | ph2 (1,0) stage b0 | ph3 (1,1)
// stage a1 | ph4 (0,1, re-read a0) stage b1. vmcnt(4) at ends of ph1/ph2/ph4
// (gates a1(t), b1(t), a0+b0(t+1) resp., each staged >=2-3 phases earlier).
__global__ __launch_bounds__(512, 2) void gemm_p1(
    const unsigned short* __restrict__ A,
    const unsigned short* __restrict__ B0_v, const unsigned short* __restrict__ B1_v,
    const unsigned short* __restrict__ B0_l, const unsigned short* __restrict__ B1_l,
    unsigned short* __restrict__ H,
    const int* __restrict__ counts)
{
    __shared__ unsigned short Ls[2][512 * 64];   // 128 KiB

    const int m0 = blockIdx.y * 256;
    const int padNv = counts[0], padTot = counts[1];
    if (m0 >= padTot) return;
    const int expert = (m0 >= padNv);
    const unsigned short* Wg = expert ? B0_l : B0_v;
    const unsigned short* Wu = expert ? B1_l : B1_v;

    const int tid  = threadIdx.x;
    const int wid  = tid >> 6;     // 0..7
    const int lane = tid & 63;
    const int wr   = wid >> 2;     // 0..1
    const int wc   = wid & 3;      // 0..3
    const int n0   = blockIdx.x * 128;

    // staging: pre-swizzled global source, linear LDS dest
    const int cs   = ((lane & 7) ^ (lane >> 3)) * 8;
    const int rsub = wid * 8 + (lane >> 3);          // 0..63
    const int dW   = wid * 8 * 64;                   // wave-uniform (shorts)

    const unsigned short* pA0 = A  + (size_t)(m0 +   0 + rsub) * DIM + cs;
    const unsigned short* pA1 = A  + (size_t)(m0 +  64 + rsub) * DIM + cs;
    const unsigned short* pA2 = A  + (size_t)(m0 + 128 + rsub) * DIM + cs;
    const unsigned short* pA3 = A  + (size_t)(m0 + 192 + rsub) * DIM + cs;
    const unsigned short* pG0 = Wg + (size_t)(n0 +   0 + rsub) * DIM + cs;
    const unsigned short* pG1 = Wg + (size_t)(n0 +  64 + rsub) * DIM + cs;
    const unsigned short* pU0 = Wu + (size_t)(n0 +   0 + rsub) * DIM + cs;
    const unsigned short* pU1 = Wu + (size_t)(n0 +  64 + rsub) * DIM + cs;

    unsigned short* L0 = &Ls[0][0];
    unsigned short* L1 = &Ls[1][0];

#define GLD(p, Ld, dst, ko) __builtin_amdgcn_global_load_lds( \
        (const GAS void*)((p) + (ko)), (LAS void*)&(Ld)[(dst) + dW], 16, 0, 0)
#define STA0(Ld, ko) do { GLD(pA0, Ld,   0 * 64, ko); GLD(pA1, Ld,  64 * 64, ko); } while (0)
#define STA1(Ld, ko) do { GLD(pA2, Ld, 128 * 64, ko); GLD(pA3, Ld, 192 * 64, ko); } while (0)
#define STB0(Ld, ko) do { GLD(pG0, Ld, 256 * 64, ko); GLD(pG1, Ld, 320 * 64, ko); } while (0)
#define STB1(Ld, ko) do { GLD(pU0, Ld, 384 * 64, ko); GLD(pU1, Ld, 448 * 64, ko); } while (0)
#define BAR() do { asm volatile("" ::: "memory"); \
        __builtin_amdgcn_s_barrier(); asm volatile("" ::: "memory"); } while (0)

    const int rlo = lane & 15;
    const int sw7 = rlo & 7;
    bf16x8 af[4][2], bB[2][2];

#define READA(Lc, QA) do { \
    _Pragma("unroll") \
    for (int kh = 0; kh < 2; ++kh) { \
        const int swoff = (((lane >> 4) + kh * 4) ^ sw7) * 8; \
        _Pragma("unroll") \
        for (int i = 0; i < 4; ++i) \
            af[i][kh] = *reinterpret_cast<const bf16x8*>( \
                &(Lc)[((QA) * 128 + wr * 64 + i * 16 + rlo) * 64 + swoff]); \
    } } while (0)
#define READB(Lc, QB) do { \
    _Pragma("unroll") \
    for (int kh = 0; kh < 2; ++kh) { \
        const int swoff = (((lane >> 4) + kh * 4) ^ sw7) * 8; \
        _Pragma("unroll") \
        for (int j = 0; j < 2; ++j) \
            bB[j][kh] = *reinterpret_cast<const bf16x8*>( \
                &(Lc)[(256 + (QB) * 128 + wc * 32 + j * 16 + rlo) * 64 + swoff]); \
    } } while (0)
#define MFMAQ(QA, ACC) do { \
    __builtin_amdgcn_s_setprio(1); \
    _Pragma("unroll") \
    for (int kh = 0; kh < 2; ++kh) \
        _Pragma("unroll") \
        for (int i = 0; i < 4; ++i) \
            _Pragma("unroll") \
            for (int j = 0; j < 2; ++j) \
                ACC[QA][i][j] = __builtin_amdgcn_mfma_f32_16x16x32_bf16( \
                    af[i][kh], bB[j][kh], ACC[QA][i][j], 0, 0, 0); \
    __builtin_amdgcn_s_setprio(0); } while (0)

    f32x4 accg[2][4][2], accu[2][4][2];
#pragma unroll
    for (int qa = 0; qa < 2; ++qa)
#pragma unroll
        for (int i = 0; i < 4; ++i)
#pragma unroll
            for (int j = 0; j < 2; ++j) {
                accg[qa][i][j] = (f32x4){0.f, 0.f, 0.f, 0.f};
                accu[qa][i][j] = (f32x4){0.f, 0.f, 0.f, 0.f};
            }

    // prologue: tile0 -> buf0 (FIFO order a0,b0,a1,b1), full drain once.
    STA0(L0, 0); STB0(L0, 0); STA1(L0, 0); STB1(L0, 0);
    asm volatile("s_waitcnt vmcnt(0)" ::: "memory");
    BAR();

    const int NKT = DIM / 64;   // 16

    // main tiles t = 0..14: compute buf (t&1), stage tile t+1 into other buf.
#pragma unroll 1
    for (int t = 0; t < NKT - 1; ++t) {
        unsigned short* Lc = (t & 1) ? L1 : L0;
        unsigned short* Ln = (t & 1) ? L0 : L1;
        const int ko = (t + 1) * 64;

        // ph1: (qa0, qb0=gate); stage a0(t+1)
        READA(Lc, 0); READB(Lc, 0);
        STA0(Ln, ko);
        BAR();
        asm volatile("s_waitcnt lgkmcnt(0)" ::: "memory");
        MFMAQ(0, accg);
        asm volatile("s_waitcnt vmcnt(4)" ::: "memory");   // gates a1(t) for ph2
        BAR();

        // ph2: (qa1, qb0); stage b0(t+1)
        READA(Lc, 1);
        STB0(Ln, ko);
        BAR();
        asm volatile("s_waitcnt lgkmcnt(0)" ::: "memory");
        MFMAQ(1, accg);
        asm volatile("s_waitcnt vmcnt(4)" ::: "memory");   // gates b1(t) for ph3
        BAR();

        // ph3: (qa1, qb1=up); stage a1(t+1)
        READB(Lc, 1);
        STA1(Ln, ko);
        BAR();
        asm volatile("s_waitcnt lgkmcnt(0)" ::: "memory");
        MFMAQ(1, accu);
        BAR();

        // ph4: (qa0, qb1) re-read a0; stage b1(t+1)
        READA(Lc, 0);
        STB1(Ln, ko);
        BAR();
        asm volatile("s_waitcnt lgkmcnt(0)" ::: "memory");
        MFMAQ(0, accu);
        asm volatile("s_waitcnt vmcnt(4)" ::: "memory");   // gates a0,b0(t+1) for ph1
        BAR();
    }

    // last tile t = 15 in buf1: no staging; waits peel to vmcnt(2)/vmcnt(0).
    {
        unsigned short* Lc = L1;
        READA(Lc, 0); READB(Lc, 0);
        BAR();
        asm volatile("s_waitcnt lgkmcnt(0)" ::: "memory");
        MFMAQ(0, accg);
        asm volatile("s_waitcnt vmcnt(2)" ::: "memory");   // a1(15) done (b1 may fly)
        BAR();

        READA(Lc, 1);
        BAR();
        asm volatile("s_waitcnt lgkmcnt(0)" ::: "memory");
        MFMAQ(1, accg);
        asm volatile("s_waitcnt vmcnt(0)" ::: "memory");   // b1(15) done
        BAR();

        READB(Lc, 1);
        BAR();
        asm volatile("s_waitcnt lgkmcnt(0)" ::: "memory");
        MFMAQ(1, accu);
        BAR();

        READA(Lc, 0);
        BAR();
        asm volatile("s_waitcnt lgkmcnt(0)" ::: "memory");
        MFMAQ(0, accu);
    }
#undef READA
#undef READB
#undef MFMAQ
#undef STA0
#undef STA1
#undef STB0
#undef STB1
#undef GLD
#undef BAR

    // epilogue: silu(gate) * up -> H (thread-local thanks to interleaved map)
    const int rb = m0 + wr * 64 + ((lane >> 4) * 4);
    const int cb = n0 + wc * 32 + (lane & 15);
#pragma unroll
    for (int qa = 0; qa < 2; ++qa)
#pragma unroll
        for (int i = 0; i < 4; ++i)
#pragma unroll
            for (int reg = 0; reg < 4; ++reg) {
                const int row = rb + qa * 128 + i * 16 + reg;
#pragma unroll
                for (int j = 0; j < 2; ++j) {
                    const float g = accg[qa][i][j][reg];
                    const float u = accu[qa][i][j][reg];
                    const float hv = g / (1.0f + __expf(-g)) * u;
                    H[(size_t)row * FFDIM + cb + j * 16] = f2bf(hv);
                }
            }
}

// ========== PHASE 2: 128x128 down-proj, split-K=2, BK=64, 2-deep vmcnt(8) (r15) ==========
__global__ __launch_bounds__(256, 2) void gemm_p2(
    const unsigned short* __restrict__ A,
    const unsigned short* __restrict__ Bd_v, const unsigned short* __restrict__ Bd_l,
    unsigned short* __restrict__ P,
    const int* __restrict__ counts)
{
    __shared__ unsigned short Ls[2][256 * 64];   // 64 KiB

    const int m0 = blockIdx.y * 128;
    const int padNv = counts[0], padTot = counts[1];
    if (m0 >= padTot) return;
    const unsigned short* B0 = (m0 >= padNv) ? Bd_l : Bd_v;

    const int tid  = threadIdx.x;
    const int wid  = tid >> 6;
    const int lane = tid & 63;
    const int wr   = wid >> 1;
    const int wc   = wid & 1;
    const int n0   = blockIdx.x * 128;
    const int kbase = blockIdx.z * (FFDIM / 2);

    constexpr int NI = 8;
    const unsigned short* src[NI];
    int loff[NI];
    const int cs = ((lane & 7) ^ (lane >> 3)) * 8;
#pragma unroll
    for (int i = 0; i < NI; ++i) {
        const int g = wid * 64 + i * 8 + (lane >> 3);   // 0..255
        const unsigned short* p = (g < 128)
            ? A + (size_t)(m0 + g) * FFDIM
            : B0 + (size_t)(n0 + g - 128) * FFDIM;
        src[i] = p + kbase + cs;
        loff[i] = (wid * 64 + i * 8) * 64;
    }

#define STAGE2(buf, kkt) do { \
    const int _c = (kkt) * 64; \
    _Pragma("unroll") \
    for (int i = 0; i < NI; ++i) \
        __builtin_amdgcn_global_load_lds((const GAS void*)(src[i] + _c), \
                                         (LAS void*)&Ls[buf][loff[i]], 16, 0, 0); \
} while (0)

    const int rlo = lane & 15;
    const int sw7 = rlo & 7;

    f32x4 acc[4][4];
#pragma unroll
    for (int i = 0; i < 4; ++i)
#pragma unroll
        for (int j = 0; j < 4; ++j)
            acc[i][j] = (f32x4){0.f, 0.f, 0.f, 0.f};

    STAGE2(0, 0);

    const int NKT = (FFDIM / 2) / 64;  // 32
    bf16x8 af[4], bf[4];
#pragma unroll 1
    for (int kt = 0; kt < NKT; ++kt) {
        const int cur = kt & 1;

        asm volatile("" ::: "memory");
        __builtin_amdgcn_s_barrier();      // prev readers of buf cur^1 done
        asm volatile("" ::: "memory");

        if (kt + 1 < NKT) {
            STAGE2(cur ^ 1, kt + 1);
            asm volatile("s_waitcnt vmcnt(8)" ::: "memory");  // own cur loads done
        } else {
            asm volatile("s_waitcnt vmcnt(0)" ::: "memory");
        }

        asm volatile("" ::: "memory");
        __builtin_amdgcn_s_barrier();      // all waves' cur loads visible
        asm volatile("" ::: "memory");

#pragma unroll
        for (int kh = 0; kh < 2; ++kh) {
            const int kc    = (lane >> 4) + kh * 4;
            const int swoff = (kc ^ sw7) * 8;
#pragma unroll
            for (int i = 0; i < 4; ++i)
                af[i] = *reinterpret_cast<const bf16x8*>(&Ls[cur][(wr * 64 + i * 16 + rlo) * 64 + swoff]);
#pragma unroll
            for (int j = 0; j < 4; ++j)
                bf[j] = *reinterpret_cast<const bf16x8*>(&Ls[cur][(128 + wc * 64 + j * 16 + rlo) * 64 + swoff]);

            __builtin_amdgcn_s_setprio(1);
#pragma unroll
            for (int i = 0; i < 4; ++i)
#pragma unroll
                for (int j = 0; j < 4; ++j)
                    acc[i][j] = __builtin_amdgcn_mfma_f32_16x16x32_bf16(af[i], bf[j], acc[i][j], 0, 0, 0);
            __builtin_amdgcn_s_setprio(0);
        }
    }
#undef STAGE2

    unsigned short* Pz = P + (size_t)blockIdx.z * MAXPAD * DIM;
    const int rbase = m0 + wr * 64 + ((lane >> 4) * 4);
    const int cin   = lane & 15;
#pragma unroll
    for (int i = 0; i < 4; ++i)
#pragma unroll
        for (int reg = 0; reg < 4; ++reg) {
            const int row = rbase + i * 16 + reg;
#pragma unroll
            for (int j = 0; j < 4; ++j)
                Pz[(size_t)row * DIM + n0 + wc * 64 + j * 16 + cin] = f2bf(acc[i][j][reg]);
        }
}

// ---------- reduce: out[src_of[row]] = f32(P0[row]) + f32(P1[row]) ----------
__global__ void reduce_kernel(const unsigned short* __restrict__ P,
                              const int* __restrict__ src_of,
                              float* __restrict__ O) {
    const int gid = blockIdx.x * 256 + threadIdx.x;   // MAXPAD*128 threads
    const int row = gid >> 7;
    const int c   = (gid & 127) * 8;
    const int src = src_of[row];
    if (src < 0) return;
    const us8 a = *reinterpret_cast<const us8*>(P + (size_t)row * DIM + c);
    const us8 b = *reinterpret_cast<const us8*>(P + (size_t)(MAXPAD + row) * DIM + c);
    float4 o0, o1;
    o0.x = bf2f(a.v[0]) + bf2f(b.v[0]);
    o0.y = bf2f(a.v[1]) + bf2f(b.v[1]);
    o0.z = bf2f(a.v[2]) + bf2f(b.v[2]);
    o0.w = bf2f(a.v[3]) + bf2f(b.v[3]);
    o1.x = bf2f(a.v[4]) + bf2f(b.v[4]);
    o1.y = bf2f(a.v[5]) + bf2f(b.v[5]);
    o1.z = bf2f(a.v[6]) + bf2f(b.v[6]);
    o1.w = bf2f(a.v[7]) + bf2f(b.v[7]);
    float* dst = O + (size_t)src * DIM + c;
    *reinterpret_cast<float4*>(dst)     = o0;
    *reinterpret_cast<float4*>(dst + 4) = o1;
}

extern "C" void kernel_launch(void* const* d_in, const int* in_sizes, int n_in,
                              void* d_out, int out_size, void* d_ws, size_t ws_size,
                              hipStream_t stream) {
    const float* hs = (const float*)d_in[0];
    const int*   tt = (const int*)d_in[1];
    const float* w_vg = (const float*)d_in[2];
    const float* w_vu = (const float*)d_in[3];
    const float* w_vd = (const float*)d_in[4];
    const float* w_lg = (const float*)d_in[5];
    const float* w_lu = (const float*)d_in[6];
    const float* w_ld = (const float*)d_in[7];
    float* out = (float*)d_out;
    char* ws = (char*)d_ws;

    const size_t MATB = (size_t)FFDIM * DIM * 2;             // 8 MiB
    const size_t XGB  = (size_t)MAXPAD * DIM * 2;            // 9.44 MB
    const size_t HSZ  = (size_t)MAXPAD * FFDIM * 2;          // 37.75 MB

    int* counts = (int*)ws;
    int* src_of = (int*)(ws + 64);
    unsigned short* Xg = (unsigned short*)(ws + 32768);

    const int NELEM = FFDIM * DIM;
    const size_t need_big = 32768 + XGB + 6 * MATB + HSZ;    // ~93 MiB

    scan_kernel<<<1, 1024, 0, stream>>>(tt, src_of, counts);

    if (ws_size >= need_big) {
        // big layout: all 6 weights own slots; Part aliases dead gate/up region
        unsigned short* Wg_v = (unsigned short*)(ws + 32768 + XGB);
        unsigned short* Wu_v = (unsigned short*)(ws + 32768 + XGB + MATB);
        unsigned short* Wg_l = (unsigned short*)(ws + 32768 + XGB + MATB * 2);
        unsigned short* Wu_l = (unsigned short*)(ws + 32768 + XGB + MATB * 3);
        unsigned short* Wd_v = (unsigned short*)(ws + 32768 + XGB + MATB * 4);
        unsigned short* Wd_l = (unsigned short*)(ws + 32768 + XGB + MATB * 5);
        unsigned short* H    = (unsigned short*)(ws + 32768 + XGB + MATB * 6);
        unsigned short* Part = Wg_v;   // 18.9 MB over 32 MB dead-after-p1 region

        dim3 gp(MAXPAD * 128 / 256, 7);
        prep_kernel<<<gp, 256, 0, stream>>>(hs, src_of, Xg,
                                            w_vg, w_vu, w_lg, w_lu, w_vd, w_ld,
                                            Wg_v, Wu_v, Wg_l, Wu_l, Wd_v, Wd_l);

        dim3 g1(FFDIM / 128, MAXPAD / 256);   // 32 x 18, 512 threads
        gemm_p1<<<g1, 512, 0, stream>>>(Xg, Wg_v, Wu_v, Wg_l, Wu_l, H, counts);

        dim3 g2(DIM / 128, MAXPAD / 128, 2);  // 8 x 36 x 2
        gemm_p2<<<g2, 256, 0, stream>>>(H, Wd_v, Wd_l, Part, counts);

        reduce_kernel<<<MAXPAD * 128 / 256, 256, 0, stream>>>(Part, src_of, out);
    } else {
        // fallback: r15/r16 layout/order (Wd + Part alias dead regions)
        unsigned short* Wg_v = (unsigned short*)(ws + 32768 + XGB);
        unsigned short* Wu_v = (unsigned short*)(ws + 32768 + XGB + MATB);
        unsigned short* Wg_l = (unsigned short*)(ws + 32768 + XGB + MATB * 2);
        unsigned short* Wu_l = (unsigned short*)(ws + 32768 + XGB + MATB * 3);
        unsigned short* H    = (unsigned short*)(ws + 32768 + XGB + MATB * 4);
        unsigned short* Wd_v = (unsigned short*)(ws + 32768);
        unsigned short* Wd_l = (unsigned short*)(ws + 32768 + MATB);
        unsigned short* Part = (unsigned short*)(ws + 32768 + MATB * 2);

        gather_cast<<<MAXPAD * 128 / 256, 256, 0, stream>>>(hs, src_of, Xg);

        dim3 gc4(NELEM / 2048, 4);
        cast4_kernel<<<gc4, 256, 0, stream>>>(w_vg, w_vu, w_lg, w_lu, Wg_v, Wu_v, Wg_l, Wu_l);

        dim3 g1(FFDIM / 128, MAXPAD / 256);
        gemm_p1<<<g1, 512, 0, stream>>>(Xg, Wg_v, Wu_v, Wg_l, Wu_l, H, counts);

        dim3 gc2(NELEM / 2048, 2);
        cast2_kernel<<<gc2, 256, 0, stream>>>(w_vd, w_ld, Wd_v, Wd_l);

        dim3 g2(DIM / 128, MAXPAD / 128, 2);
        gemm_p2<<<g2, 256, 0, stream>>>(H, Wd_v, Wd_l, Part, counts);

        reduce_kernel<<<MAXPAD * 128 / 256, 256, 0, stream>>>(Part, src_of, out);
    }
}

// Round 5
// 177.064 us; speedup vs baseline: 1.1145x; 1.1145x over previous
//
#include <hip/hip_runtime.h>
#include <hip/hip_bf16.h>
#include <stdint.h>

// PatchedVisionExpertMLP — round 21
//   Phase-split arc CLOSED after 3 failed ports (MfmaUtil 23-28% each; m152's
//   "exact barrier placement" warning empirically confirmed). This round:
//   occupancy levers on the PROVEN r16 structure instead.
//   (1) p1: __launch_bounds__(256,4) — regs 56+64agpr=120<=128 fits 4 blk/CU,
//       LDS 4x32K=128K<=160K fits; was only guaranteed 2.
//   (2) p2: converted from 64K dbuf+vmcnt(8) (~850TF) to the p1-style single
//       32K buffer + vmcnt(0) drain (~950TF on p1's shape), no setprio (m190),
//       __launch_bounds__(256,4) -> 4 blk/CU (was LDS-capped at 2).
//   Everything else frozen at r19 (prep fusion, shuffle scan, pad 128).

#define TOKENS 4096
#define SEQ    2048
#define DIM    1024
#define FFDIM  4096
#define MAXPAD 4608

typedef __attribute__((ext_vector_type(8))) short bf16x8;
typedef __attribute__((ext_vector_type(4))) float f32x4;

#define GAS __attribute__((address_space(1)))
#define LAS __attribute__((address_space(3)))

__device__ inline unsigned short f2bf(float x) {
    union { float f; unsigned int u; } c; c.f = x;
    unsigned int r = c.u + 0x7FFFu + ((c.u >> 16) & 1u);  // RNE
    return (unsigned short)(r >> 16);
}
__device__ inline float bf2f(unsigned short u) {
    union { unsigned int i; float f; } c; c.i = ((unsigned int)u) << 16;
    return c.f;
}

struct __align__(16) us8 { unsigned short v[8]; };

// ---------- scan: group tokens by expert, pad each segment to 128 ----------
__global__ __launch_bounds__(1024) void scan_kernel(const int* __restrict__ tt,
                                                    int* __restrict__ src_of,
                                                    int* __restrict__ counts) {
    __shared__ int wsum[16];
    const int tid  = threadIdx.x;
    const int lane = tid & 63;
    const int wav  = tid >> 6;

    for (int i = tid; i < MAXPAD; i += 1024) src_of[i] = -1;

    const int t0 = tid * 4;
    int v[4], cnt = 0;
#pragma unroll
    for (int j = 0; j < 4; ++j) {
        const int t = t0 + j;
        const int l = t & (SEQ - 1);
        int vis = 0;
        if (l < SEQ - 1) vis = (tt[t] == 1) & (tt[t + 1] == 1);
        v[j] = vis; cnt += vis;
    }

    int s = cnt;
#pragma unroll
    for (int off = 1; off < 64; off <<= 1) {
        const int o = __shfl_up(s, off, 64);
        if (lane >= off) s += o;
    }
    if (lane == 63) wsum[wav] = s;
    __syncthreads();
    if (wav == 0 && lane < 16) {
        int w = wsum[lane];
#pragma unroll
        for (int off = 1; off < 16; off <<= 1) {
            const int o = __shfl_up(w, off, 16);
            if (lane >= off) w += o;
        }
        wsum[lane] = w;
    }
    __syncthreads();

    const int wbase  = wav ? wsum[wav - 1] : 0;
    const int incl   = wbase + s;
    const int excl   = incl - cnt;
    const int totalV = wsum[15];
    const int padNv  = (totalV + 127) & ~127;
    int pv = excl;
    int pl = padNv + (t0 - excl);
#pragma unroll
    for (int j = 0; j < 4; ++j) {
        const int t = t0 + j;
        if (v[j]) src_of[pv++] = t; else src_of[pl++] = t;
    }
    if (tid == 0) {
        const int Nl = TOKENS - totalV;
        counts[0] = padNv;
        counts[1] = padNv + ((Nl + 127) & ~127);
    }
}

__device__ inline void gather_body(const float* __restrict__ hs, const int* __restrict__ src_of,
                                   unsigned short* __restrict__ Xg, int gid) {
    const int row = gid >> 7;
    const int c   = (gid & 127) * 8;
    const int src = src_of[row];
    us8 o;
    if (src >= 0) {
        const float4 a = *reinterpret_cast<const float4*>(hs + (size_t)src * DIM + c);
        const float4 b = *reinterpret_cast<const float4*>(hs + (size_t)src * DIM + c + 4);
        o.v[0] = f2bf(a.x); o.v[1] = f2bf(a.y); o.v[2] = f2bf(a.z); o.v[3] = f2bf(a.w);
        o.v[4] = f2bf(b.x); o.v[5] = f2bf(b.y); o.v[6] = f2bf(b.z); o.v[7] = f2bf(b.w);
    } else {
#pragma unroll
        for (int j = 0; j < 8; ++j) o.v[j] = 0;
    }
    *reinterpret_cast<us8*>(Xg + (size_t)row * DIM + c) = o;
}

__global__ void gather_cast(const float* __restrict__ hs, const int* __restrict__ src_of,
                            unsigned short* __restrict__ Xg) {
    gather_body(hs, src_of, Xg, blockIdx.x * 256 + threadIdx.x);
}

__device__ inline void cast8(const float* __restrict__ in, unsigned short* __restrict__ out, int i) {
    const float4 a = *reinterpret_cast<const float4*>(in + i);
    const float4 b = *reinterpret_cast<const float4*>(in + i + 4);
    us8 o;
    o.v[0] = f2bf(a.x); o.v[1] = f2bf(a.y); o.v[2] = f2bf(a.z); o.v[3] = f2bf(a.w);
    o.v[4] = f2bf(b.x); o.v[5] = f2bf(b.y); o.v[6] = f2bf(b.z); o.v[7] = f2bf(b.w);
    *reinterpret_cast<us8*>(out + i) = o;
}

// ---------- fused prep: y==0 -> gather+cast X; y=1..6 -> cast weight matrix ----------
__global__ void prep_kernel(const float* __restrict__ hs, const int* __restrict__ src_of,
                            unsigned short* __restrict__ Xg,
                            const float* __restrict__ s0, const float* __restrict__ s1,
                            const float* __restrict__ s2, const float* __restrict__ s3,
                            const float* __restrict__ s4, const float* __restrict__ s5,
                            unsigned short* __restrict__ d0, unsigned short* __restrict__ d1,
                            unsigned short* __restrict__ d2, unsigned short* __restrict__ d3,
                            unsigned short* __restrict__ d4, unsigned short* __restrict__ d5) {
    const int m = blockIdx.y;
    if (m == 0) {
        gather_body(hs, src_of, Xg, blockIdx.x * 256 + threadIdx.x);
    } else {
        const int i = (blockIdx.x * 256 + threadIdx.x) * 8;
        if (i >= FFDIM * DIM) return;
        const float* s = (m == 1) ? s0 : (m == 2) ? s1 : (m == 3) ? s2 : (m == 4) ? s3 : (m == 5) ? s4 : s5;
        unsigned short* d = (m == 1) ? d0 : (m == 2) ? d1 : (m == 3) ? d2 : (m == 4) ? d3 : (m == 5) ? d4 : d5;
        cast8(s, d, i);
    }
}

__global__ void cast4_kernel(const float* __restrict__ s0, const float* __restrict__ s1,
                             const float* __restrict__ s2, const float* __restrict__ s3,
                             unsigned short* __restrict__ d0, unsigned short* __restrict__ d1,
                             unsigned short* __restrict__ d2, unsigned short* __restrict__ d3) {
    const int i = (blockIdx.x * 256 + threadIdx.x) * 8;
    const int m = blockIdx.y;
    const float* s = (m == 0) ? s0 : (m == 1) ? s1 : (m == 2) ? s2 : s3;
    unsigned short* d = (m == 0) ? d0 : (m == 1) ? d1 : (m == 2) ? d2 : d3;
    cast8(s, d, i);
}

__global__ void cast2_kernel(const float* __restrict__ s0, const float* __restrict__ s1,
                             unsigned short* __restrict__ d0, unsigned short* __restrict__ d1) {
    const int i = (blockIdx.x * 256 + threadIdx.x) * 8;
    const float* s = blockIdx.y ? s1 : s0;
    unsigned short* d = blockIdx.y ? d1 : d0;
    cast8(s, d, i);
}

// ========== PHASE 1: 128x(64g|64u) GEMM, BK=64, 32 KiB LDS, vmcnt(0) ==========
// r16-proven structure; launch_bounds min-waves 2 -> 4 (regs 56+64agpr=120<=128).
__global__ __launch_bounds__(256, 4) void gemm_p1(
    const unsigned short* __restrict__ A,
    const unsigned short* __restrict__ B0_v, const unsigned short* __restrict__ B1_v,
    const unsigned short* __restrict__ B0_l, const unsigned short* __restrict__ B1_l,
    unsigned short* __restrict__ H,
    const int* __restrict__ counts)
{
    __shared__ unsigned short Ls[256 * 64];   // 32 KiB

    const int m0 = blockIdx.y * 128;
    const int padNv = counts[0], padTot = counts[1];
    if (m0 >= padTot) return;
    const int expert = (m0 >= padNv);
    const unsigned short* B0 = expert ? B0_l : B0_v;
    const unsigned short* B1 = expert ? B1_l : B1_v;

    const int tid  = threadIdx.x;
    const int wid  = tid >> 6;
    const int lane = tid & 63;
    const int n0   = blockIdx.x * 64;

    constexpr int NI = 8;
    const unsigned short* src[NI];
    int loff[NI];
    const int cs = ((lane & 7) ^ (lane >> 3)) * 8;   // pre-swizzled chunk (elems)
#pragma unroll
    for (int i = 0; i < NI; ++i) {
        const int g = wid * 64 + i * 8 + (lane >> 3);  // 0..255
        const unsigned short* p;
        if (g < 128) {
            p = A + (size_t)(m0 + g) * DIM;
        } else {
            const int br = g - 128;
            p = (br < 64) ? (B0 + (size_t)(n0 + br) * DIM) : (B1 + (size_t)(n0 + br - 64) * DIM);
        }
        src[i] = p + cs;
        loff[i] = (wid * 64 + i * 8) * 64;             // shorts, wave-uniform
    }

    const int rlo = lane & 15;
    const int sw7 = rlo & 7;

    f32x4 acc[2][8];
#pragma unroll
    for (int i = 0; i < 2; ++i)
#pragma unroll
        for (int j = 0; j < 8; ++j)
            acc[i][j] = (f32x4){0.f, 0.f, 0.f, 0.f};

    const int NKT = DIM / 64;   // 16
#pragma unroll 1
    for (int kt = 0; kt < NKT; ++kt) {
        if (kt) __syncthreads();
        const int c = kt * 64;
#pragma unroll
        for (int i = 0; i < NI; ++i)
            __builtin_amdgcn_global_load_lds((const GAS void*)(src[i] + c),
                                             (LAS void*)&Ls[loff[i]], 16, 0, 0);
        asm volatile("s_waitcnt vmcnt(0)" ::: "memory");
        __syncthreads();

#pragma unroll
        for (int kh = 0; kh < 2; ++kh) {
            const int kc    = (lane >> 4) + kh * 4;
            const int swoff = (kc ^ sw7) * 8;
            const bf16x8 af0 = *reinterpret_cast<const bf16x8*>(&Ls[(wid * 32 + rlo) * 64 + swoff]);
            const bf16x8 af1 = *reinterpret_cast<const bf16x8*>(&Ls[(wid * 32 + 16 + rlo) * 64 + swoff]);
#pragma unroll
            for (int n = 0; n < 8; ++n) {
                const bf16x8 bfr = *reinterpret_cast<const bf16x8*>(&Ls[(128 + n * 16 + rlo) * 64 + swoff]);
                acc[0][n] = __builtin_amdgcn_mfma_f32_16x16x32_bf16(af0, bfr, acc[0][n], 0, 0, 0);
                acc[1][n] = __builtin_amdgcn_mfma_f32_16x16x32_bf16(af1, bfr, acc[1][n], 0, 0, 0);
            }
        }
    }

    const int rbase = m0 + wid * 32 + ((lane >> 4) * 4);
    const int cin   = lane & 15;
#pragma unroll
    for (int fr = 0; fr < 2; ++fr)
#pragma unroll
        for (int reg = 0; reg < 4; ++reg) {
            const int row = rbase + fr * 16 + reg;
#pragma unroll
            for (int n = 0; n < 4; ++n) {
                const float g = acc[fr][n][reg];
                const float u = acc[fr][n + 4][reg];
                const float h = g / (1.0f + __expf(-g)) * u;
                H[(size_t)row * FFDIM + n0 + n * 16 + cin] = f2bf(h);
            }
        }
}

// ========== PHASE 2: 128x128 down-proj, split-K=2, BK=64, single 32 KiB buffer ==========
// Converted to the p1-proven loop (stage -> vmcnt(0) -> barrier -> MFMA), no
// setprio (m190: null/negative on lockstep GEMM); 4 blk/CU now LDS-feasible.
__global__ __launch_bounds__(256, 4) void gemm_p2(
    const unsigned short* __restrict__ A,
    const unsigned short* __restrict__ Bd_v, const unsigned short* __restrict__ Bd_l,
    unsigned short* __restrict__ P,
    const int* __restrict__ counts)
{
    __shared__ unsigned short Ls[256 * 64];   // 32 KiB

    const int m0 = blockIdx.y * 128;
    const int padNv = counts[0], padTot = counts[1];
    if (m0 >= padTot) return;
    const unsigned short* B0 = (m0 >= padNv) ? Bd_l : Bd_v;

    const int tid  = threadIdx.x;
    const int wid  = tid >> 6;
    const int lane = tid & 63;
    const int wr   = wid >> 1;
    const int wc   = wid & 1;
    const int n0   = blockIdx.x * 128;
    const int kbase = blockIdx.z * (FFDIM / 2);

    constexpr int NI = 8;
    const unsigned short* src[NI];
    int loff[NI];
    const int cs = ((lane & 7) ^ (lane >> 3)) * 8;
#pragma unroll
    for (int i = 0; i < NI; ++i) {
        const int g = wid * 64 + i * 8 + (lane >> 3);   // 0..255
        const unsigned short* p = (g < 128)
            ? A + (size_t)(m0 + g) * FFDIM
            : B0 + (size_t)(n0 + g - 128) * FFDIM;
        src[i] = p + kbase + cs;
        loff[i] = (wid * 64 + i * 8) * 64;
    }

    const int rlo = lane & 15;
    const int sw7 = rlo & 7;

    f32x4 acc[4][4];
#pragma unroll
    for (int i = 0; i < 4; ++i)
#pragma unroll
        for (int j = 0; j < 4; ++j)
            acc[i][j] = (f32x4){0.f, 0.f, 0.f, 0.f};

    const int NKT = (FFDIM / 2) / 64;  // 32
    bf16x8 af[4], bf[4];
#pragma unroll 1
    for (int kt = 0; kt < NKT; ++kt) {
        if (kt) __syncthreads();
        const int c = kt * 64;
#pragma unroll
        for (int i = 0; i < NI; ++i)
            __builtin_amdgcn_global_load_lds((const GAS void*)(src[i] + c),
                                             (LAS void*)&Ls[loff[i]], 16, 0, 0);
        asm volatile("s_waitcnt vmcnt(0)" ::: "memory");
        __syncthreads();

#pragma unroll
        for (int kh = 0; kh < 2; ++kh) {
            const int kc    = (lane >> 4) + kh * 4;
            const int swoff = (kc ^ sw7) * 8;
#pragma unroll
            for (int i = 0; i < 4; ++i)
                af[i] = *reinterpret_cast<const bf16x8*>(&Ls[(wr * 64 + i * 16 + rlo) * 64 + swoff]);
#pragma unroll
            for (int j = 0; j < 4; ++j)
                bf[j] = *reinterpret_cast<const bf16x8*>(&Ls[(128 + wc * 64 + j * 16 + rlo) * 64 + swoff]);

#pragma unroll
            for (int i = 0; i < 4; ++i)
#pragma unroll
                for (int j = 0; j < 4; ++j)
                    acc[i][j] = __builtin_amdgcn_mfma_f32_16x16x32_bf16(af[i], bf[j], acc[i][j], 0, 0, 0);
        }
    }

    unsigned short* Pz = P + (size_t)blockIdx.z * MAXPAD * DIM;
    const int rbase = m0 + wr * 64 + ((lane >> 4) * 4);
    const int cin   = lane & 15;
#pragma unroll
    for (int i = 0; i < 4; ++i)
#pragma unroll
        for (int reg = 0; reg < 4; ++reg) {
            const int row = rbase + i * 16 + reg;
#pragma unroll
            for (int j = 0; j < 4; ++j)
                Pz[(size_t)row * DIM + n0 + wc * 64 + j * 16 + cin] = f2bf(acc[i][j][reg]);
        }
}

// ---------- reduce: out[src_of[row]] = f32(P0[row]) + f32(P1[row]) ----------
__global__ void reduce_kernel(const unsigned short* __restrict__ P,
                              const int* __restrict__ src_of,
                              float* __restrict__ O) {
    const int gid = blockIdx.x * 256 + threadIdx.x;   // MAXPAD*128 threads
    const int row = gid >> 7;
    const int c   = (gid & 127) * 8;
    const int src = src_of[row];
    if (src < 0) return;
    const us8 a = *reinterpret_cast<const us8*>(P + (size_t)row * DIM + c);
    const us8 b = *reinterpret_cast<const us8*>(P + (size_t)(MAXPAD + row) * DIM + c);
    float4 o0, o1;
    o0.x = bf2f(a.v[0]) + bf2f(b.v[0]);
    o0.y = bf2f(a.v[1]) + bf2f(b.v[1]);
    o0.z = bf2f(a.v[2]) + bf2f(b.v[2]);
    o0.w = bf2f(a.v[3]) + bf2f(b.v[3]);
    o1.x = bf2f(a.v[4]) + bf2f(b.v[4]);
    o1.y = bf2f(a.v[5]) + bf2f(b.v[5]);
    o1.z = bf2f(a.v[6]) + bf2f(b.v[6]);
    o1.w = bf2f(a.v[7]) + bf2f(b.v[7]);
    float* dst = O + (size_t)src * DIM + c;
    *reinterpret_cast<float4*>(dst)     = o0;
    *reinterpret_cast<float4*>(dst + 4) = o1;
}

extern "C" void kernel_launch(void* const* d_in, const int* in_sizes, int n_in,
                              void* d_out, int out_size, void* d_ws, size_t ws_size,
                              hipStream_t stream) {
    const float* hs = (const float*)d_in[0];
    const int*   tt = (const int*)d_in[1];
    const float* w_vg = (const float*)d_in[2];
    const float* w_vu = (const float*)d_in[3];
    const float* w_vd = (const float*)d_in[4];
    const float* w_lg = (const float*)d_in[5];
    const float* w_lu = (const float*)d_in[6];
    const float* w_ld = (const float*)d_in[7];
    float* out = (float*)d_out;
    char* ws = (char*)d_ws;

    const size_t MATB = (size_t)FFDIM * DIM * 2;             // 8 MiB
    const size_t XGB  = (size_t)MAXPAD * DIM * 2;            // 9.44 MB
    const size_t HSZ  = (size_t)MAXPAD * FFDIM * 2;          // 37.75 MB

    int* counts = (int*)ws;
    int* src_of = (int*)(ws + 64);
    unsigned short* Xg = (unsigned short*)(ws + 32768);

    const int NELEM = FFDIM * DIM;
    const size_t need_big = 32768 + XGB + 6 * MATB + HSZ;    // ~93 MiB

    scan_kernel<<<1, 1024, 0, stream>>>(tt, src_of, counts);

    if (ws_size >= need_big) {
        // big layout: all 6 weights own slots; Part aliases dead gate/up region
        unsigned short* Wg_v = (unsigned short*)(ws + 32768 + XGB);
        unsigned short* Wu_v = (unsigned short*)(ws + 32768 + XGB + MATB);
        unsigned short* Wg_l = (unsigned short*)(ws + 32768 + XGB + MATB * 2);
        unsigned short* Wu_l = (unsigned short*)(ws + 32768 + XGB + MATB * 3);
        unsigned short* Wd_v = (unsigned short*)(ws + 32768 + XGB + MATB * 4);
        unsigned short* Wd_l = (unsigned short*)(ws + 32768 + XGB + MATB * 5);
        unsigned short* H    = (unsigned short*)(ws + 32768 + XGB + MATB * 6);
        unsigned short* Part = Wg_v;   // 18.9 MB over 32 MB dead-after-p1 region

        dim3 gp(MAXPAD * 128 / 256, 7);
        prep_kernel<<<gp, 256, 0, stream>>>(hs, src_of, Xg,
                                            w_vg, w_vu, w_lg, w_lu, w_vd, w_ld,
                                            Wg_v, Wu_v, Wg_l, Wu_l, Wd_v, Wd_l);

        dim3 g1(FFDIM / 64, MAXPAD / 128);    // 64 x 36
        gemm_p1<<<g1, 256, 0, stream>>>(Xg, Wg_v, Wu_v, Wg_l, Wu_l, H, counts);

        dim3 g2(DIM / 128, MAXPAD / 128, 2);  // 8 x 36 x 2
        gemm_p2<<<g2, 256, 0, stream>>>(H, Wd_v, Wd_l, Part, counts);

        reduce_kernel<<<MAXPAD * 128 / 256, 256, 0, stream>>>(Part, src_of, out);
    } else {
        // fallback: r15/r16 layout/order (Wd + Part alias dead regions)
        unsigned short* Wg_v = (unsigned short*)(ws + 32768 + XGB);
        unsigned short* Wu_v = (unsigned short*)(ws + 32768 + XGB + MATB);
        unsigned short* Wg_l = (unsigned short*)(ws + 32768 + XGB + MATB * 2);
        unsigned short* Wu_l = (unsigned short*)(ws + 32768 + XGB + MATB * 3);
        unsigned short* H    = (unsigned short*)(ws + 32768 + XGB + MATB * 4);
        unsigned short* Wd_v = (unsigned short*)(ws + 32768);
        unsigned short* Wd_l = (unsigned short*)(ws + 32768 + MATB);
        unsigned short* Part = (unsigned short*)(ws + 32768 + MATB * 2);

        gather_cast<<<MAXPAD * 128 / 256, 256, 0, stream>>>(hs, src_of, Xg);

        dim3 gc4(NELEM / 2048, 4);
        cast4_kernel<<<gc4, 256, 0, stream>>>(w_vg, w_vu, w_lg, w_lu, Wg_v, Wu_v, Wg_l, Wu_l);

        dim3 g1(FFDIM / 64, MAXPAD / 128);
        gemm_p1<<<g1, 256, 0, stream>>>(Xg, Wg_v, Wu_v, Wg_l, Wu_l, H, counts);

        dim3 gc2(NELEM / 2048, 2);
        cast2_kernel<<<gc2, 256, 0, stream>>>(w_vd, w_ld, Wd_v, Wd_l);

        dim3 g2(DIM / 128, MAXPAD / 128, 2);
        gemm_p2<<<g2, 256, 0, stream>>>(H, Wd_v, Wd_l, Part, counts);

        reduce_kernel<<<MAXPAD * 128 / 256, 256, 0, stream>>>(Part, src_of, out);
    }
}